// Round 1
// baseline (821.262 us; speedup 1.0000x reference)
//
#include <hip/hip_runtime.h>
#include <hip/hip_bf16.h>
#include <math.h>

// Problem constants
#define L_ 1024
#define B_ 4
#define D_ 1024
#define E_ 8
#define K_ 2
#define H_ 4096
#define T_ (L_*B_)        // 4096 tokens
#define P_ (T_*K_)        // 8192 token-expert pairs (always exactly T*K)
#define PPAD (P_+128)     // padded rows so partial GEMM tiles can over-read safely

typedef unsigned short u16;
typedef __attribute__((ext_vector_type(4))) float f32x4;
typedef __attribute__((ext_vector_type(8))) short s16x8;

__device__ __forceinline__ u16 f2bf(float f) {
  uint32_t u = __float_as_uint(f);
  uint32_t r = (u + 0x7FFFu + ((u >> 16) & 1u)) >> 16;  // RNE
  return (u16)r;
}
__device__ __forceinline__ float gelu_tanh(float v) {
  float c = v + 0.044715f * v * v * v;
  return 0.5f * v * (1.0f + tanhf(0.7978845608028654f * c));
}

// ---------------------------------------------------------------------------
// fp32 [E][R][C] -> bf16 [E][C][R]  (transpose + convert, 64x64 LDS tiles)
// ---------------------------------------------------------------------------
template<int R, int C>
__global__ void convtrans(const float* __restrict__ in, u16* __restrict__ out) {
  __shared__ float tile[64][65];
  int e = blockIdx.z;
  int r0 = blockIdx.y * 64, c0 = blockIdx.x * 64;
  const float* src = in + (size_t)e * R * C;
  u16* dst = out + (size_t)e * R * C;
  int t = threadIdx.x;
  int tr = t >> 4, tc = (t & 15) * 4;
#pragma unroll
  for (int p = 0; p < 4; ++p) {
    int r = tr + p * 16;
    float4 v = *(const float4*)(src + (size_t)(r0 + r) * C + c0 + tc);
    tile[r][tc] = v.x; tile[r][tc+1] = v.y; tile[r][tc+2] = v.z; tile[r][tc+3] = v.w;
  }
  __syncthreads();
#pragma unroll
  for (int p = 0; p < 4; ++p) {
    int c = tr + p * 16;
    ushort4 o;
    o.x = f2bf(tile[tc+0][c]); o.y = f2bf(tile[tc+1][c]);
    o.z = f2bf(tile[tc+2][c]); o.w = f2bf(tile[tc+3][c]);
    *(ushort4*)(dst + (size_t)(c0 + c) * R + r0 + tc) = o;
  }
}

// ---------------------------------------------------------------------------
// Gating: one wave per token. fp32 logits (must match reference top-k).
// ---------------------------------------------------------------------------
__global__ void gating(const float* __restrict__ x, const float* __restrict__ task_param,
                       const float* __restrict__ gw_img, const float* __restrict__ gb_img,
                       const float* __restrict__ gw_txt, const float* __restrict__ gb_txt,
                       const float* __restrict__ tgw, const float* __restrict__ tgb,
                       const float* __restrict__ alpha_p, const int* __restrict__ is_text_p,
                       float4* __restrict__ sel_w, float* __restrict__ prob_part,
                       int* __restrict__ count_part) {
  __shared__ float wprob[4][8];
  __shared__ int wcnt[4][8];
  int wid = threadIdx.x >> 6, lane = threadIdx.x & 63;
  int t = blockIdx.x * 4 + wid;
  int b = t & (B_ - 1);
  int it = is_text_p[0];
  const float* gw = it ? gw_txt : gw_img;
  const float* gb = it ? gb_txt : gb_img;
  float alpha = alpha_p[0];
  const float* xr = x + (size_t)t * D_;
  const float* tp = task_param + (size_t)b * D_;
  float acc[8] = {0,0,0,0,0,0,0,0};
  float tac[8] = {0,0,0,0,0,0,0,0};
  for (int i = 0; i < D_/64; ++i) {
    int d = i * 64 + lane;
    float xv = xr[d], tv = tp[d];
#pragma unroll
    for (int e = 0; e < 8; ++e) {
      acc[e] += xv * gw[d*8 + e];
      tac[e] += tv * tgw[d*8 + e];
    }
  }
#pragma unroll
  for (int e = 0; e < 8; ++e) {
#pragma unroll
    for (int off = 32; off > 0; off >>= 1) {
      acc[e] += __shfl_xor(acc[e], off);
      tac[e] += __shfl_xor(tac[e], off);
    }
  }
  float lg[8];
#pragma unroll
  for (int e = 0; e < 8; ++e)
    lg[e] = (1.0f - alpha) * (acc[e] + gb[e]) + alpha * (tac[e] + tgb[e]);
  // full softmax (for l_aux)
  float m = lg[0];
#pragma unroll
  for (int e = 1; e < 8; ++e) m = fmaxf(m, lg[e]);
  float pr[8], ps = 0.f;
#pragma unroll
  for (int e = 0; e < 8; ++e) { pr[e] = expf(lg[e] - m); ps += pr[e]; }
  float inv = 1.0f / ps;
  // top-2 (ties -> lowest index, matching lax.top_k)
  int i0 = 0; float v0 = lg[0];
#pragma unroll
  for (int e = 1; e < 8; ++e) if (lg[e] > v0) { v0 = lg[e]; i0 = e; }
  int i1 = -1; float v1 = -1e30f;
#pragma unroll
  for (int e = 0; e < 8; ++e) if (e != i0 && lg[e] > v1) { v1 = lg[e]; i1 = e; }
  float ex = expf(v1 - v0);
  float w0 = 1.0f / (1.0f + ex), w1 = ex / (1.0f + ex);
  if (lane == 0) {
    sel_w[t] = make_float4(__int_as_float(i0), __int_as_float(i1), w0, w1);
#pragma unroll
    for (int e = 0; e < 8; ++e) {
      wprob[wid][e] = pr[e] * inv;
      wcnt[wid][e] = (i0 == e) + (i1 == e);
    }
  }
  __syncthreads();
  if (threadIdx.x < 8) {
    int e = threadIdx.x;
    prob_part[blockIdx.x * 8 + e] = wprob[0][e] + wprob[1][e] + wprob[2][e] + wprob[3][e];
    count_part[blockIdx.x * 8 + e] = wcnt[0][e] + wcnt[1][e] + wcnt[2][e] + wcnt[3][e];
  }
}

// ---------------------------------------------------------------------------
// Finalize: deterministic reduce of partials -> counts/offsets/cursors + l_aux
// ---------------------------------------------------------------------------
__global__ void finalize(const float* __restrict__ prob_part, const int* __restrict__ count_part,
                         int* __restrict__ counts, int* __restrict__ offs,
                         int* __restrict__ cursors, float* __restrict__ laux_out) {
  __shared__ float ps_[256];
  __shared__ int cs_[256];
  int t = threadIdx.x;
  int e = t & 7, s = t >> 3;  // 32 strided chunks per expert
  float p = 0.f; int c = 0;
  for (int b = s; b < 1024; b += 32) { p += prob_part[b*8 + e]; c += count_part[b*8 + e]; }
  ps_[t] = p; cs_[t] = c;
  __syncthreads();
  for (int st = 16; st > 0; st >>= 1) {
    if (s < st) { ps_[t] += ps_[t + st*8]; cs_[t] += cs_[t + st*8]; }
    __syncthreads();
  }
  if (t == 0) {
    int off = 0; float laux = 0.f;
    for (int ee = 0; ee < 8; ++ee) {
      int cnt = cs_[ee];
      counts[ee] = cnt; offs[ee] = off; cursors[ee] = off; off += cnt;
      laux += (ps_[ee] * (1.0f/4096.0f)) * ((float)cnt * (1.0f/4096.0f));
    }
    *laux_out = laux;
  }
}

// ---------------------------------------------------------------------------
// Scatter + gather: assign bucket slots, record token->pair map, gather bf16 rows
// ---------------------------------------------------------------------------
__global__ void scatter_gather(const float* __restrict__ x, const float4* __restrict__ sel_w,
                               int* __restrict__ cursors, float* __restrict__ pair_w,
                               int* __restrict__ pair_idx, u16* __restrict__ Xg) {
  int wid = threadIdx.x >> 6, lane = threadIdx.x & 63;
  int t = blockIdx.x * 4 + wid;
  float4 sw = sel_w[t];
  int s0 = __float_as_int(sw.x), s1 = __float_as_int(sw.y);
  int p0 = 0, p1 = 0;
  if (lane == 0) {
    p0 = atomicAdd(&cursors[s0], 1);
    p1 = atomicAdd(&cursors[s1], 1);
  }
  p0 = __shfl(p0, 0); p1 = __shfl(p1, 0);
  if (lane == 0) {
    pair_w[p0] = sw.z; pair_w[p1] = sw.w;
    pair_idx[t*2] = p0; pair_idx[t*2+1] = p1;
  }
  const float* xr = x + (size_t)t * D_;
  u16* d0 = Xg + (size_t)p0 * D_;
  u16* d1 = Xg + (size_t)p1 * D_;
#pragma unroll
  for (int i = 0; i < 4; ++i) {
    int c = i * 256 + lane * 4;
    float4 v = *(const float4*)(xr + c);
    ushort4 o;
    o.x = f2bf(v.x); o.y = f2bf(v.y); o.z = f2bf(v.z); o.w = f2bf(v.w);
    *(ushort4*)(d0 + c) = o;
    *(ushort4*)(d1 + c) = o;
  }
}

// ---------------------------------------------------------------------------
// Grouped GEMM (bf16 MFMA 16x16x32, 128x128 tile, BK=32, global_load_lds w16)
// A: rows x KDIM bf16 (row-major).  B: per-expert NDIM x KDIM bf16 (K contiguous).
// EPI==0: Hout[row][n] = bf16(gelu(acc))   EPI==1: Cout[row][n] = acc * pair_w[row]
// ---------------------------------------------------------------------------
template<int EPI, int KDIM, int NDIM>
__global__ void gemm_ffn(const u16* __restrict__ A, const u16* __restrict__ Bmat,
                         const int* __restrict__ counts, const int* __restrict__ offs,
                         const float* __restrict__ pair_w,
                         u16* __restrict__ Hout, float* __restrict__ Cout) {
  int e = blockIdx.z;
  int ne = counts[e];
  int bx = blockIdx.x;
  if (bx * 128 >= ne) return;
  int off = offs[e];
  int n0 = blockIdx.y * 128;
  __shared__ u16 As[128 * 32];
  __shared__ u16 Bs[128 * 32];
  int t = threadIdx.x;
  int lane = t & 63, wid = t >> 6;
  int wm = (wid >> 1) * 64, wn = (wid & 1) * 64;
  const u16* Ag = A + (size_t)(off + bx * 128) * KDIM;
  const u16* Bg = Bmat + (size_t)e * NDIM * KDIM + (size_t)n0 * KDIM;
  int crow = t >> 2, ccol = (t & 3) * 8;  // 16B chunk per thread
  f32x4 acc[4][4] = {};
  int lr = lane & 15, lk = (lane >> 4) * 8;
  for (int k0 = 0; k0 < KDIM; k0 += 32) {
    __builtin_amdgcn_global_load_lds(
        (const __attribute__((address_space(1))) void*)(Ag + (size_t)crow * KDIM + k0 + ccol),
        (__attribute__((address_space(3))) void*)(As + t * 8), 16, 0, 0);
    __builtin_amdgcn_global_load_lds(
        (const __attribute__((address_space(1))) void*)(Ag + (size_t)(crow + 64) * KDIM + k0 + ccol),
        (__attribute__((address_space(3))) void*)(As + 2048 + t * 8), 16, 0, 0);
    __builtin_amdgcn_global_load_lds(
        (const __attribute__((address_space(1))) void*)(Bg + (size_t)crow * KDIM + k0 + ccol),
        (__attribute__((address_space(3))) void*)(Bs + t * 8), 16, 0, 0);
    __builtin_amdgcn_global_load_lds(
        (const __attribute__((address_space(1))) void*)(Bg + (size_t)(crow + 64) * KDIM + k0 + ccol),
        (__attribute__((address_space(3))) void*)(Bs + 2048 + t * 8), 16, 0, 0);
    __syncthreads();
    s16x8 af[4], bfv[4];
#pragma unroll
    for (int r = 0; r < 4; ++r) af[r] = *(const s16x8*)(As + (wm + r * 16 + lr) * 32 + lk);
#pragma unroll
    for (int f = 0; f < 4; ++f) bfv[f] = *(const s16x8*)(Bs + (wn + f * 16 + lr) * 32 + lk);
#pragma unroll
    for (int r = 0; r < 4; ++r)
#pragma unroll
      for (int f = 0; f < 4; ++f)
        acc[r][f] = __builtin_amdgcn_mfma_f32_16x16x32_bf16(af[r], bfv[f], acc[r][f], 0, 0, 0);
    __syncthreads();
  }
  int lg4 = (lane >> 4) * 4;
#pragma unroll
  for (int r = 0; r < 4; ++r) {
#pragma unroll
    for (int j = 0; j < 4; ++j) {
      int mloc = bx * 128 + wm + r * 16 + lg4 + j;
      if (mloc >= ne) continue;
      size_t grow = (size_t)(off + mloc);
      if (EPI == 0) {
#pragma unroll
        for (int f = 0; f < 4; ++f) {
          float v = acc[r][f][j];
          Hout[grow * NDIM + n0 + wn + f * 16 + lr] = f2bf(gelu_tanh(v));
        }
      } else {
        float w = pair_w[grow];
#pragma unroll
        for (int f = 0; f < 4; ++f) {
          Cout[grow * NDIM + n0 + wn + f * 16 + lr] = acc[r][f][j] * w;
        }
      }
    }
  }
}

// ---------------------------------------------------------------------------
// Combine: out[token] = pair_out[p0] + pair_out[p1]
// ---------------------------------------------------------------------------
__global__ void combine(const float* __restrict__ pair_out, const int* __restrict__ pair_idx,
                        float* __restrict__ out) {
  int t = blockIdx.x;
  int p0 = pair_idx[t*2], p1 = pair_idx[t*2+1];
  int c = threadIdx.x * 4;
  float4 a = *(const float4*)(pair_out + (size_t)p0 * D_ + c);
  float4 b = *(const float4*)(pair_out + (size_t)p1 * D_ + c);
  float4 o; o.x = a.x + b.x; o.y = a.y + b.y; o.z = a.z + b.z; o.w = a.w + b.w;
  *(float4*)(out + (size_t)t * D_ + c) = o;
}

// ---------------------------------------------------------------------------
// Workspace layout (bytes) — requires ~210 MiB of d_ws.
//   w1b  [E][H][D] bf16 @ 0           (67108864)  <- aliased by pair_out later
//   w2b  [E][D][H] bf16 @ 67108864    (67108864)
//   Xg   [PPAD][D] bf16 @ 134217728   (17039360)
//   Hb   [PPAD][H] bf16 @ 151257088   (68157440)
//   sel_w    @ 219414528 (65536)
//   pair_w   @ 219480064 (33280)
//   pair_idx @ 219513344 (32768)
//   prob_part@ 219546112 (32768)
//   count_part@219578880 (32768)
//   counters @ 219611648 (counts[8], offs[8], cursors[8])
//   pair_out [PPAD][D] f32 @ 0 (34078720, aliases dead w1b)
// ---------------------------------------------------------------------------
extern "C" void kernel_launch(void* const* d_in, const int* in_sizes, int n_in,
                              void* d_out, int out_size, void* d_ws, size_t ws_size,
                              hipStream_t stream) {
  const float* inputs      = (const float*)d_in[0];
  const float* task_param  = (const float*)d_in[1];
  const float* gate_img_w  = (const float*)d_in[2];
  const float* gate_img_b  = (const float*)d_in[3];
  const float* gate_txt_w  = (const float*)d_in[4];
  const float* gate_txt_b  = (const float*)d_in[5];
  const float* task_gate_w = (const float*)d_in[6];
  const float* task_gate_b = (const float*)d_in[7];
  const float* alpha       = (const float*)d_in[8];
  const float* w1          = (const float*)d_in[9];
  const float* w2          = (const float*)d_in[10];
  const int*   is_text     = (const int*)d_in[11];
  float* out = (float*)d_out;

  char* ws = (char*)d_ws;
  u16* w1b = (u16*)(ws + 0);
  u16* w2b = (u16*)(ws + 67108864);
  u16* Xg  = (u16*)(ws + 134217728);
  u16* Hb  = (u16*)(ws + 151257088);
  float4* sel_w   = (float4*)(ws + 219414528);
  float* pair_w   = (float*)(ws + 219480064);
  int* pair_idx   = (int*)(ws + 219513344);
  float* prob_part= (float*)(ws + 219546112);
  int* count_part = (int*)(ws + 219578880);
  int* counters   = (int*)(ws + 219611648);
  float* pair_out = (float*)(ws + 0);  // aliases w1b (dead after GEMM1)

  int* counts  = counters;
  int* offs    = counters + 8;
  int* cursors = counters + 16;

  convtrans<D_, H_><<<dim3(H_/64, D_/64, E_), 256, 0, stream>>>(w1, w1b);
  convtrans<H_, D_><<<dim3(D_/64, H_/64, E_), 256, 0, stream>>>(w2, w2b);
  gating<<<dim3(T_/4), 256, 0, stream>>>(inputs, task_param, gate_img_w, gate_img_b,
      gate_txt_w, gate_txt_b, task_gate_w, task_gate_b, alpha, is_text,
      sel_w, prob_part, count_part);
  finalize<<<dim3(1), 256, 0, stream>>>(prob_part, count_part, counts, offs, cursors,
      out + (size_t)T_ * D_);
  scatter_gather<<<dim3(T_/4), 256, 0, stream>>>(inputs, sel_w, cursors, pair_w, pair_idx, Xg);
  gemm_ffn<0, D_, H_><<<dim3(32, H_/128, E_), 256, 0, stream>>>(
      Xg, w1b, counts, offs, pair_w, Hb, (float*)nullptr);
  gemm_ffn<1, H_, D_><<<dim3(32, D_/128, E_), 256, 0, stream>>>(
      Hb, w2b, counts, offs, pair_w, (u16*)nullptr, pair_out);
  combine<<<dim3(T_), 256, 0, stream>>>(pair_out, pair_idx, out);
}